// Round 2
// baseline (149.593 us; speedup 1.0000x reference)
//
#include <hip/hip_runtime.h>

#define NPTS 512
#define BLOCK 256
#define XPS 68   // xp row stride (dwords): mult of 4 (16B rows), mod 32 = 4 staggers banks

// ---------------------------------------------------------------------------
// Kernel 1: per-batch weighted moments — R10: max-concurrency VGPR streaming.
//
// Falsification ledger:
//   R3-R8: six load structures (5x VGPR variants, 1x global_load_lds) all cap
//          at 2.76-2.95 TB/s logical read, every pipe <15% busy.
//   R9:    NT (no-allocate) cache policy on global_load_lds -> NULL (143.5 vs
//          144.5 us). Eviction/allocation theory dead.
// Revised theory: pipe-idle at 44% of BW = LATENCY/CONCURRENCY-bound, not
// BW-bound. All prior variants shared one invariant: ~112 KB/CU in-flight
// read window (32 waves x 3.5 KB staged into 17 KB LDS, drained by a
// vmcnt(0) barrier). The load instruction never mattered; the window did.
//
// R10: one WAVE = one batch. Lane l owns points {4l..4l+3, 4l+256..4l+259}:
// 14 independent dwordx4 loads issued up-front (3 src + 3 tgt + 1 w per
// half-batch; the 4-point = 3-float4 alignment makes VGPR layout exact).
// 14 KB/wave in flight, ~16 waves/CU (VGPR ~110) => ~224 KB/CU window, 2x
// prior. ZERO __syncthreads: reduction is the proven wave-private
// xp[16][68] transpose + quarter-sum (4x ds_read_b128) + 2x shfl_xor.
//   - If concurrency-bound: moments ~40 -> 20-26 us, total -> ~125 us.
//   - If unchanged: 2.9 TB/s read cap survives 2x window + 0 barriers ->
//     genuine ceiling at 93% -> ROOFLINE.
// ---------------------------------------------------------------------------
__global__ __launch_bounds__(BLOCK) void wproc_moments(
    const float* __restrict__ src,
    const float* __restrict__ tgt,
    const float* __restrict__ wts,
    float* __restrict__ ws,
    int B)
{
    const int t = threadIdx.x;
    const int wave = t >> 6, lane = t & 63;
    const int b = blockIdx.x * 4 + wave;   // one wave per batch

    __shared__ __align__(16) float xp[4][16][XPS];   // 17408 B, wave-private rows

    if (b >= B) return;   // uniform per wave; no barriers anywhere below

    const float4* sb = (const float4*)(src + (size_t)b * (NPTS * 3)); // 384 f4
    const float4* tb = (const float4*)(tgt + (size_t)b * (NPTS * 3)); // 384 f4
    const float4* wb = (const float4*)(wts + (size_t)b * NPTS);       // 128 f4

    // ---- issue all 14 independent dwordx4 loads up front ----
    // half 0: points 4l..4l+3 ; half 1: points 4l+256..4l+259
    const float4 w0  = wb[lane];
    const float4 s0a = sb[3 * lane + 0];
    const float4 s0b = sb[3 * lane + 1];
    const float4 s0c = sb[3 * lane + 2];
    const float4 t0a = tb[3 * lane + 0];
    const float4 t0b = tb[3 * lane + 1];
    const float4 t0c = tb[3 * lane + 2];
    const float4 w1  = wb[lane + 64];
    const float4 s1a = sb[3 * lane + 192];
    const float4 s1b = sb[3 * lane + 193];
    const float4 s1c = sb[3 * lane + 194];
    const float4 t1a = tb[3 * lane + 192];
    const float4 t1b = tb[3 * lane + 193];
    const float4 t1c = tb[3 * lane + 194];

    // ---- accumulate 16 moments over 8 points, straight from VGPRs ----
    // [W, m_s(3), m_t(3), M(9) row-major M_ij = sum w*src_i*tgt_j]
    float acc[16];
    #pragma unroll
    for (int i = 0; i < 16; ++i) acc[i] = 0.f;

    #define ACC_PT(w_, sx, sy, sz, tx, ty, tz) do {                          \
        const float w = ((w_) < 0.f) ? 0.f : (w_);  /* WEIGHT_THRESHOLD=0 */ \
        acc[0] += w;                                                          \
        acc[1] += w * (sx); acc[2] += w * (sy); acc[3] += w * (sz);           \
        acc[4] += w * (tx); acc[5] += w * (ty); acc[6] += w * (tz);           \
        const float wsx = w * (sx), wsy = w * (sy), wsz = w * (sz);           \
        acc[7]  += wsx * (tx); acc[8]  += wsx * (ty); acc[9]  += wsx * (tz);  \
        acc[10] += wsy * (tx); acc[11] += wsy * (ty); acc[12] += wsy * (tz);  \
        acc[13] += wsz * (tx); acc[14] += wsz * (ty); acc[15] += wsz * (tz);  \
    } while (0)

    ACC_PT(w0.x, s0a.x, s0a.y, s0a.z, t0a.x, t0a.y, t0a.z);
    ACC_PT(w0.y, s0a.w, s0b.x, s0b.y, t0a.w, t0b.x, t0b.y);
    ACC_PT(w0.z, s0b.z, s0b.w, s0c.x, t0b.z, t0b.w, t0c.x);
    ACC_PT(w0.w, s0c.y, s0c.z, s0c.w, t0c.y, t0c.z, t0c.w);
    ACC_PT(w1.x, s1a.x, s1a.y, s1a.z, t1a.x, t1a.y, t1a.z);
    ACC_PT(w1.y, s1a.w, s1b.x, s1b.y, t1a.w, t1b.x, t1b.y);
    ACC_PT(w1.z, s1b.z, s1b.w, s1c.x, t1b.z, t1b.w, t1c.x);
    ACC_PT(w1.w, s1c.y, s1c.z, s1c.w, t1c.y, t1c.z, t1c.w);
    #undef ACC_PT

    // ---- wave-private reduction: transpose, quarter-sum, shfl combine ----
    // DS ops are in-order within a wave: no barrier needed.
    #pragma unroll
    for (int m = 0; m < 16; ++m) xp[wave][m][lane] = acc[m];

    const int m = lane & 15, q = lane >> 4;
    const float4* row = (const float4*)&xp[wave][m][0] + 4 * q;
    float4 a0 = row[0], a1 = row[1], a2 = row[2], a3 = row[3];
    a0.x += a1.x; a0.y += a1.y; a0.z += a1.z; a0.w += a1.w;
    a2.x += a3.x; a2.y += a3.y; a2.z += a3.z; a2.w += a3.w;
    a0.x += a2.x; a0.y += a2.y; a0.z += a2.z; a0.w += a2.w;
    float v = (a0.x + a0.y) + (a0.z + a0.w);
    v += __shfl_xor(v, 16, 64);
    v += __shfl_xor(v, 32, 64);
    if (q == 0) ws[(size_t)b * 16 + m] = v;
}

// ---------------------------------------------------------------------------
// Kernel 2: per-batch 3x3 Procrustes solve, one lane per batch — 128 dense
// f64 chains total (R6 proved per-wave fusion inflates this 64x; keep split).
//
// Algebra: with T = sum(w)+eps:
//   H = M/T - (2 - W/T) * (m_s/T)(m_t/T)^T   (exact expansion of centered cov)
// SVD-free rotation: Jacobi eigendecomp of A = H^T H -> V; v3 := v1 x v2,
// u_i = H v_i (Gram-Schmidt), u3 := u1 x u2; R = V U^T. Cross products force
// det(U)=det(V)=+1 == reference's diag(1,1,sign(det)) reflection fix.
// ---------------------------------------------------------------------------
__global__ __launch_bounds__(BLOCK) void wproc_solve(
    const float* __restrict__ ws,
    float* __restrict__ out,
    int B)
{
    const int b = blockIdx.x * BLOCK + threadIdx.x;
    if (b >= B) return;

    double m[16];
    #pragma unroll
    for (int i = 0; i < 16; ++i) m[i] = (double)ws[(size_t)b * 16 + i];

    const double T = m[0] + 1e-5;       // sum(w) + EPS
    const double f = 2.0 - m[0] / T;
    const double cs[3] = { m[1] / T, m[2] / T, m[3] / T };
    const double ct[3] = { m[4] / T, m[5] / T, m[6] / T };
    double H[3][3];
    for (int i = 0; i < 3; ++i)
        for (int j = 0; j < 3; ++j)
            H[i][j] = m[7 + i * 3 + j] / T - f * cs[i] * ct[j];

    // A = H^T H (symmetric PSD)
    double A[3][3];
    for (int i = 0; i < 3; ++i)
        for (int j = 0; j < 3; ++j)
            A[i][j] = H[0][i] * H[0][j] + H[1][i] * H[1][j] + H[2][i] * H[2][j];

    // Jacobi eigendecomposition: A = V diag V^T
    double V[3][3] = { {1, 0, 0}, {0, 1, 0}, {0, 0, 1} };
    for (int sweep = 0; sweep < 5; ++sweep) {
        for (int pair = 0; pair < 3; ++pair) {
            const int p = (pair == 2) ? 1 : 0;
            const int q = (pair == 0) ? 1 : 2;
            const double apq = A[p][q];
            if (apq == 0.0) continue;
            const double theta = (A[q][q] - A[p][p]) / (2.0 * apq);
            const double tt = ((theta >= 0.0) ? 1.0 : -1.0)
                            / (fabs(theta) + sqrt(theta * theta + 1.0));
            const double c = 1.0 / sqrt(tt * tt + 1.0);
            const double sn = tt * c;
            for (int k = 0; k < 3; ++k) {  // A <- A G
                const double akp = A[k][p], akq = A[k][q];
                A[k][p] = c * akp - sn * akq;
                A[k][q] = sn * akp + c * akq;
            }
            for (int k = 0; k < 3; ++k) {  // A <- G^T A
                const double apk = A[p][k], aqk = A[q][k];
                A[p][k] = c * apk - sn * aqk;
                A[q][k] = sn * apk + c * aqk;
            }
            for (int k = 0; k < 3; ++k) {  // V <- V G
                const double vkp = V[k][p], vkq = V[k][q];
                V[k][p] = c * vkp - sn * vkq;
                V[k][q] = sn * vkp + c * vkq;
            }
        }
    }

    // sort eigenpairs descending
    const double lam[3] = { A[0][0], A[1][1], A[2][2] };
    int i0 = 0, i1 = 1, i2 = 2;
    if (lam[i0] < lam[i1]) { int tmp = i0; i0 = i1; i1 = tmp; }
    if (lam[i0] < lam[i2]) { int tmp = i0; i0 = i2; i2 = tmp; }
    if (lam[i1] < lam[i2]) { int tmp = i1; i1 = i2; i2 = tmp; }

    const double v1[3] = { V[0][i0], V[1][i0], V[2][i0] };
    const double v2[3] = { V[0][i1], V[1][i1], V[2][i1] };
    const double v3[3] = { v1[1] * v2[2] - v1[2] * v2[1],
                           v1[2] * v2[0] - v1[0] * v2[2],
                           v1[0] * v2[1] - v1[1] * v2[0] };

    double u1[3], u2[3], u3[3];
    for (int i = 0; i < 3; ++i)
        u1[i] = H[i][0] * v1[0] + H[i][1] * v1[1] + H[i][2] * v1[2];
    double n1 = sqrt(u1[0] * u1[0] + u1[1] * u1[1] + u1[2] * u1[2]);
    n1 = (n1 > 1e-30) ? n1 : 1e-30;
    for (int i = 0; i < 3; ++i) u1[i] /= n1;

    for (int i = 0; i < 3; ++i)
        u2[i] = H[i][0] * v2[0] + H[i][1] * v2[1] + H[i][2] * v2[2];
    const double d12 = u1[0] * u2[0] + u1[1] * u2[1] + u1[2] * u2[2];
    for (int i = 0; i < 3; ++i) u2[i] -= d12 * u1[i];
    double n2 = sqrt(u2[0] * u2[0] + u2[1] * u2[1] + u2[2] * u2[2]);
    n2 = (n2 > 1e-30) ? n2 : 1e-30;
    for (int i = 0; i < 3; ++i) u2[i] /= n2;

    u3[0] = u1[1] * u2[2] - u1[2] * u2[1];
    u3[1] = u1[2] * u2[0] - u1[0] * u2[2];
    u3[2] = u1[0] * u2[1] - u1[1] * u2[0];

    double R[3][3];
    for (int i = 0; i < 3; ++i)
        for (int j = 0; j < 3; ++j)
            R[i][j] = v1[i] * u1[j] + v2[i] * u2[j] + v3[i] * u3[j];

    double tv[3];
    for (int i = 0; i < 3; ++i)
        tv[i] = ct[i] - (R[i][0] * cs[0] + R[i][1] * cs[1] + R[i][2] * cs[2]);

    float* outR = out + (size_t)b * 9;
    for (int i = 0; i < 3; ++i)
        for (int j = 0; j < 3; ++j)
            outR[i * 3 + j] = (float)R[i][j];
    float* outT = out + (size_t)B * 9 + (size_t)b * 3;
    for (int i = 0; i < 3; ++i) outT[i] = (float)tv[i];
}

extern "C" void kernel_launch(void* const* d_in, const int* in_sizes, int n_in,
                              void* d_out, int out_size, void* d_ws, size_t ws_size,
                              hipStream_t stream) {
    const float* src = (const float*)d_in[0];
    const float* tgt = (const float*)d_in[1];
    const float* wts = (const float*)d_in[2];
    float* out = (float*)d_out;
    float* ws = (float*)d_ws;   // 16 floats per batch = 512 KB
    const int B = out_size / 12;  // 9 (R) + 3 (t) floats per batch; B=8192

    wproc_moments<<<(B + 3) / 4, BLOCK, 0, stream>>>(src, tgt, wts, ws, B);
    wproc_solve<<<(B + BLOCK - 1) / BLOCK, BLOCK, 0, stream>>>(ws, out, B);
}

// Round 3
// 135.379 us; speedup vs baseline: 1.1050x; 1.1050x over previous
//
#include <hip/hip_runtime.h>

#define NPTS 512
#define BLOCK 256
#define BLOCK_S 64
#define XPS 68   // xp row stride (dwords): mult of 4 (16B rows), mod 32 = 4 staggers banks

#define GLOBAL_AS(p) ((const __attribute__((address_space(1))) void*)(p))
#define LDS_AS(p)    ((__attribute__((address_space(3))) void*)(p))

// ---------------------------------------------------------------------------
// Kernel 1: per-batch weighted moments — reverted to R9 (best measured:
// 143.5 us total). global_load_lds staging, NT cache policy.
//
// Read-path falsification ledger (ALL land at 2.76-2.95 TB/s logical read):
//   R3-R8: five VGPR load structures + global_load_lds staging.
//   R9:    NT (no-allocate) policy -> NULL.
//   R10:   2x in-flight window, zero barriers, wave-per-batch -> REGRESSED
//          (strided per-instr addresses de-coalesced the loads).
// Conclusion so far: ~2.9 TB/s is a robust ceiling for this streaming-read
// pattern; moments ~= 40 us. This round targets the OTHER kernel (see K2).
// ---------------------------------------------------------------------------
__global__ __launch_bounds__(BLOCK) void wproc_moments(
    const float* __restrict__ src,
    const float* __restrict__ tgt,
    const float* __restrict__ wts,
    float* __restrict__ ws)
{
    const int b = blockIdx.x;
    const int t = threadIdx.x;
    const int wave = t >> 6, lane = t & 63;

    // phase 1: 14336 B staging buffer; phase 2: xp[4][16][68] = 17408 B
    __shared__ __align__(16) char smem[4 * 16 * XPS * 4];
    __shared__ float red[4][16];

    const char* sb = (const char*)(src + (size_t)b * (NPTS * 3));
    const char* tb = (const char*)(tgt + (size_t)b * (NPTS * 3));
    const char* wb = (const char*)(wts + (size_t)b * NPTS);

    // ---- direct-to-LDS staging: 14 x 1KB chunks round-robined over waves ----
    for (int c = wave; c < 14; c += 4) {
        const char* g;
        if (c < 6)       g = sb + (size_t)c * 1024;
        else if (c < 12) g = tb + (size_t)(c - 6) * 1024;
        else             g = wb + (size_t)(c - 12) * 1024;
        __builtin_amdgcn_global_load_lds(
            GLOBAL_AS(g + lane * 16),
            LDS_AS(smem + c * 1024),
            16, 0, 2);
    }
    __syncthreads();   // compiler drains vmcnt before the barrier

    const float* s_s = (const float*)smem;            // [0, 6144)
    const float* s_t = (const float*)(smem + 6144);   // [6144, 12288)
    const float* s_w = (const float*)(smem + 12288);  // [12288, 14336)

    // ---- accumulate 16 moments over 2 points ----
    // [W, m_s(3), m_t(3), M(9) row-major M_ij = sum w*src_i*tgt_j]
    float acc[16];
    #pragma unroll
    for (int i = 0; i < 16; ++i) acc[i] = 0.f;

    #pragma unroll
    for (int k = 0; k < 2; ++k) {
        const int p = t + k * 256;
        float w = s_w[p];
        w = (w < 0.f) ? 0.f : w;  // WEIGHT_THRESHOLD = 0.0
        const float sx = s_s[3 * p + 0], sy = s_s[3 * p + 1], sz = s_s[3 * p + 2];
        const float tx = s_t[3 * p + 0], ty = s_t[3 * p + 1], tz = s_t[3 * p + 2];
        acc[0] += w;
        acc[1] += w * sx; acc[2] += w * sy; acc[3] += w * sz;
        acc[4] += w * tx; acc[5] += w * ty; acc[6] += w * tz;
        const float wsx = w * sx, wsy = w * sy, wsz = w * sz;
        acc[7]  += wsx * tx; acc[8]  += wsx * ty; acc[9]  += wsx * tz;
        acc[10] += wsy * tx; acc[11] += wsy * ty; acc[12] += wsy * tz;
        acc[13] += wsz * tx; acc[14] += wsz * ty; acc[15] += wsz * tz;
    }
    __syncthreads();   // all point reads done before xp overlays the buffer

    float (*xp)[16][XPS] = (float (*)[16][XPS])smem;
    #pragma unroll
    for (int m = 0; m < 16; ++m) xp[wave][m][lane] = acc[m];

    // wave-private: lane m+16q sums quarter q of row m (in-order DS, no barrier)
    {
        const int m = lane & 15, q = lane >> 4;
        const float4* row = (const float4*)&xp[wave][m][0] + 4 * q;
        float4 a0 = row[0], a1 = row[1], a2 = row[2], a3 = row[3];
        a0.x += a1.x; a0.y += a1.y; a0.z += a1.z; a0.w += a1.w;
        a2.x += a3.x; a2.y += a3.y; a2.z += a3.z; a2.w += a3.w;
        a0.x += a2.x; a0.y += a2.y; a0.z += a2.z; a0.w += a2.w;
        float v = (a0.x + a0.y) + (a0.z + a0.w);
        v += __shfl_xor(v, 16, 64);
        v += __shfl_xor(v, 32, 64);
        if (q == 0) red[wave][m] = v;
    }
    __syncthreads();

    if (t < 16) {
        ws[(size_t)b * 16 + t] =
            (red[0][t] + red[1][t]) + (red[2][t] + red[3][t]);
    }
}

// ---------------------------------------------------------------------------
// Kernel 2: per-batch 3x3 Procrustes solve — R11: SCRATCH-PROOF rewrite.
//
// Theory: the un-audited ~90 us gap (total 144 = moments 40 + solve ~5-10
// by op count) is solve-side SCRATCH traffic (rule #20): the eigen-sort
// produced RUNTIME indices i0/i1/i2 used as V[k][i0]/lam[i0] -> V,lam
// demoted to local memory; the Jacobi p/q loops were unroll-dependent.
// ~15 KB scratch RMW per thread x 8192 threads = ~120 MB local traffic.
//
// Fix: (a) #pragma unroll both Jacobi loops -> p,q compile-time constants;
// (b) branchless rotation (selects sanitize the apq==0 / NaN path);
// (c) eigen-sort as a STATIC compare-exchange network that physically swaps
// lam values and V columns at constant indices (pure v_cndmask selects);
// (d) 64-thread blocks x 128 -> 4x more CUs engaged.
//
// Algebra unchanged: H = M/T - (2 - W/T)(m_s/T)(m_t/T)^T; Jacobi eig of
// H^T H -> V; v3 = v1 x v2; u_i = H v_i Gram-Schmidt; u3 = u1 x u2;
// R = V U^T (det +1 by construction == reference reflection fix).
// ---------------------------------------------------------------------------
__global__ __launch_bounds__(BLOCK_S) void wproc_solve(
    const float* __restrict__ ws,
    float* __restrict__ out,
    int B)
{
    const int b = blockIdx.x * BLOCK_S + threadIdx.x;
    if (b >= B) return;

    double m[16];
    #pragma unroll
    for (int i = 0; i < 16; ++i) m[i] = (double)ws[(size_t)b * 16 + i];

    const double T = m[0] + 1e-5;       // sum(w) + EPS
    const double f = 2.0 - m[0] / T;
    const double cs[3] = { m[1] / T, m[2] / T, m[3] / T };
    const double ct[3] = { m[4] / T, m[5] / T, m[6] / T };
    double H[3][3];
    #pragma unroll
    for (int i = 0; i < 3; ++i)
        #pragma unroll
        for (int j = 0; j < 3; ++j)
            H[i][j] = m[7 + i * 3 + j] / T - f * cs[i] * ct[j];

    // A = H^T H (symmetric PSD)
    double A[3][3];
    #pragma unroll
    for (int i = 0; i < 3; ++i)
        #pragma unroll
        for (int j = 0; j < 3; ++j)
            A[i][j] = H[0][i] * H[0][j] + H[1][i] * H[1][j] + H[2][i] * H[2][j];

    // Jacobi eigendecomposition, fully unrolled, branch-free:
    // p,q are compile-time constants in every instance.
    double V[3][3] = { {1, 0, 0}, {0, 1, 0}, {0, 0, 1} };
    #pragma unroll
    for (int sweep = 0; sweep < 5; ++sweep) {
        #pragma unroll
        for (int pair = 0; pair < 3; ++pair) {
            const int p = (pair == 2) ? 1 : 0;
            const int q = (pair == 0) ? 1 : 2;
            const double apq = A[p][q];
            const double theta = (A[q][q] - A[p][p]) / (2.0 * apq);
            const double tt = ((theta >= 0.0) ? 1.0 : -1.0)
                            / (fabs(theta) + sqrt(theta * theta + 1.0));
            double c  = 1.0 / sqrt(tt * tt + 1.0);
            double sn = tt * c;
            // apq==0 -> theta inf/NaN -> select identity rotation (also
            // sanitizes any NaN propagation before it touches A/V).
            const bool zero = (apq == 0.0);
            c  = zero ? 1.0 : c;
            sn = zero ? 0.0 : sn;
            #pragma unroll
            for (int k = 0; k < 3; ++k) {  // A <- A G
                const double akp = A[k][p], akq = A[k][q];
                A[k][p] = c * akp - sn * akq;
                A[k][q] = sn * akp + c * akq;
            }
            #pragma unroll
            for (int k = 0; k < 3; ++k) {  // A <- G^T A
                const double apk = A[p][k], aqk = A[q][k];
                A[p][k] = c * apk - sn * aqk;
                A[q][k] = sn * apk + c * aqk;
            }
            #pragma unroll
            for (int k = 0; k < 3; ++k) {  // V <- V G
                const double vkp = V[k][p], vkq = V[k][q];
                V[k][p] = c * vkp - sn * vkq;
                V[k][q] = sn * vkp + c * vkq;
            }
        }
    }

    // sort eigenpairs descending via STATIC compare-exchange network:
    // physically swap lam values + V columns (constant indices, pure selects).
    double lam[3] = { A[0][0], A[1][1], A[2][2] };
    #define CSWAP(a_, b_) do {                                                \
        const bool sw_ = lam[a_] < lam[b_];                                   \
        const double tl_ = lam[a_];                                           \
        lam[a_] = sw_ ? lam[b_] : lam[a_];                                    \
        lam[b_] = sw_ ? tl_ : lam[b_];                                        \
        _Pragma("unroll")                                                     \
        for (int k = 0; k < 3; ++k) {                                         \
            const double tv_ = V[k][a_];                                      \
            V[k][a_] = sw_ ? V[k][b_] : V[k][a_];                             \
            V[k][b_] = sw_ ? tv_ : V[k][b_];                                  \
        }                                                                     \
    } while (0)
    CSWAP(0, 1); CSWAP(0, 2); CSWAP(1, 2);
    #undef CSWAP

    const double v1[3] = { V[0][0], V[1][0], V[2][0] };
    const double v2[3] = { V[0][1], V[1][1], V[2][1] };
    const double v3[3] = { v1[1] * v2[2] - v1[2] * v2[1],
                           v1[2] * v2[0] - v1[0] * v2[2],
                           v1[0] * v2[1] - v1[1] * v2[0] };

    double u1[3], u2[3], u3[3];
    #pragma unroll
    for (int i = 0; i < 3; ++i)
        u1[i] = H[i][0] * v1[0] + H[i][1] * v1[1] + H[i][2] * v1[2];
    double n1 = sqrt(u1[0] * u1[0] + u1[1] * u1[1] + u1[2] * u1[2]);
    n1 = (n1 > 1e-30) ? n1 : 1e-30;
    #pragma unroll
    for (int i = 0; i < 3; ++i) u1[i] /= n1;

    #pragma unroll
    for (int i = 0; i < 3; ++i)
        u2[i] = H[i][0] * v2[0] + H[i][1] * v2[1] + H[i][2] * v2[2];
    const double d12 = u1[0] * u2[0] + u1[1] * u2[1] + u1[2] * u2[2];
    #pragma unroll
    for (int i = 0; i < 3; ++i) u2[i] -= d12 * u1[i];
    double n2 = sqrt(u2[0] * u2[0] + u2[1] * u2[1] + u2[2] * u2[2]);
    n2 = (n2 > 1e-30) ? n2 : 1e-30;
    #pragma unroll
    for (int i = 0; i < 3; ++i) u2[i] /= n2;

    u3[0] = u1[1] * u2[2] - u1[2] * u2[1];
    u3[1] = u1[2] * u2[0] - u1[0] * u2[2];
    u3[2] = u1[0] * u2[1] - u1[1] * u2[0];

    double R[3][3];
    #pragma unroll
    for (int i = 0; i < 3; ++i)
        #pragma unroll
        for (int j = 0; j < 3; ++j)
            R[i][j] = v1[i] * u1[j] + v2[i] * u2[j] + v3[i] * u3[j];

    double tv[3];
    #pragma unroll
    for (int i = 0; i < 3; ++i)
        tv[i] = ct[i] - (R[i][0] * cs[0] + R[i][1] * cs[1] + R[i][2] * cs[2]);

    float* outR = out + (size_t)b * 9;
    #pragma unroll
    for (int i = 0; i < 3; ++i)
        #pragma unroll
        for (int j = 0; j < 3; ++j)
            outR[i * 3 + j] = (float)R[i][j];
    float* outT = out + (size_t)B * 9 + (size_t)b * 3;
    #pragma unroll
    for (int i = 0; i < 3; ++i) outT[i] = (float)tv[i];
}

extern "C" void kernel_launch(void* const* d_in, const int* in_sizes, int n_in,
                              void* d_out, int out_size, void* d_ws, size_t ws_size,
                              hipStream_t stream) {
    const float* src = (const float*)d_in[0];
    const float* tgt = (const float*)d_in[1];
    const float* wts = (const float*)d_in[2];
    float* out = (float*)d_out;
    float* ws = (float*)d_ws;   // 16 floats per batch = 512 KB
    const int B = out_size / 12;  // 9 (R) + 3 (t) floats per batch; B=8192

    wproc_moments<<<B, BLOCK, 0, stream>>>(src, tgt, wts, ws);
    wproc_solve<<<(B + BLOCK_S - 1) / BLOCK_S, BLOCK_S, 0, stream>>>(ws, out, B);
}